// Round 2
// baseline (233.017 us; speedup 1.0000x reference)
//
#include <hip/hip_runtime.h>

#define BATCH 8192
#define IN_F 4096
#define OUT_F 4096

__global__ __launch_bounds__(256) void
Rank1Linear_kernel(const float* __restrict__ x,
                   const float* __restrict__ w,
                   float* __restrict__ out) {
    const int lane = threadIdx.x & 63;
    const int row  = (blockIdx.x * blockDim.x + threadIdx.x) >> 6;  // global wave id

    // ---- 1) prefetch whole row: 16 float4/lane, all in flight (no deps) ----
    const float4* x4 = reinterpret_cast<const float4*>(x + (size_t)row * IN_F);
    float4 v[16];
#pragma unroll
    for (int j = 0; j < 16; ++j)
        v[j] = x4[j * 64 + lane];          // coalesced: 64 lanes x 16 B = 1 KiB/instr

    // ---- 2) per-lane tree sum with 4 accumulators ----
    float s0 = 0.f, s1 = 0.f, s2 = 0.f, s3 = 0.f;
#pragma unroll
    for (int j = 0; j < 16; j += 4) {
        s0 += (v[j+0].x + v[j+0].y) + (v[j+0].z + v[j+0].w);
        s1 += (v[j+1].x + v[j+1].y) + (v[j+1].z + v[j+1].w);
        s2 += (v[j+2].x + v[j+2].y) + (v[j+2].z + v[j+2].w);
        s3 += (v[j+3].x + v[j+3].y) + (v[j+3].z + v[j+3].w);
    }
    float s = (s0 + s1) + (s2 + s3);

    // ---- 3) wave-64 butterfly reduce: every lane ends with the row sum ----
#pragma unroll
    for (int m = 1; m < 64; m <<= 1)
        s += __shfl_xor(s, m, 64);

    // ---- 4) out[row,:] = s * w[:], w is L1-hot (16 KiB, every block reuses) ----
    const float4* w4 = reinterpret_cast<const float4*>(w);
    float4* o4 = reinterpret_cast<float4*>(out + (size_t)row * OUT_F);
#pragma unroll
    for (int j = 0; j < 16; ++j) {
        float4 wv = w4[j * 64 + lane];
        float4 ov;
        ov.x = s * wv.x;
        ov.y = s * wv.y;
        ov.z = s * wv.z;
        ov.w = s * wv.w;
        o4[j * 64 + lane] = ov;
    }
}

extern "C" void kernel_launch(void* const* d_in, const int* in_sizes, int n_in,
                              void* d_out, int out_size, void* d_ws, size_t ws_size,
                              hipStream_t stream) {
    const float* x = (const float*)d_in[0];   // [8192, 4096] fp32
    const float* w = (const float*)d_in[1];   // [1, 4096] fp32
    float* out = (float*)d_out;               // [8192, 4096] fp32
    // 8192 rows, one wave (64 lanes) per row, 4 waves per 256-thread block
    Rank1Linear_kernel<<<BATCH / 4, 256, 0, stream>>>(x, w, out);
}

// Round 4
// 231.765 us; speedup vs baseline: 1.0054x; 1.0054x over previous
//
#include <hip/hip_runtime.h>

#define BATCH 8192
#define IN_F 4096
#define OUT_F 4096

typedef float v4f __attribute__((ext_vector_type(4)));

// ---------- Pass 1: pure-read row sums. One wave (64 lanes) per row. ----------
__global__ __launch_bounds__(256) void
rowsum_kernel(const float* __restrict__ x, float* __restrict__ rowsum) {
    const int lane = threadIdx.x & 63;
    const int row  = (blockIdx.x * blockDim.x + threadIdx.x) >> 6;

    const v4f* x4 = reinterpret_cast<const v4f*>(x + (size_t)row * IN_F);
    v4f v[16];
#pragma unroll
    for (int j = 0; j < 16; ++j)
        v[j] = x4[j * 64 + lane];          // 16 coalesced loads, all in flight

    float s0 = 0.f, s1 = 0.f, s2 = 0.f, s3 = 0.f;
#pragma unroll
    for (int j = 0; j < 16; j += 4) {
        s0 += (v[j+0].x + v[j+0].y) + (v[j+0].z + v[j+0].w);
        s1 += (v[j+1].x + v[j+1].y) + (v[j+1].z + v[j+1].w);
        s2 += (v[j+2].x + v[j+2].y) + (v[j+2].z + v[j+2].w);
        s3 += (v[j+3].x + v[j+3].y) + (v[j+3].z + v[j+3].w);
    }
    float s = (s0 + s1) + (s2 + s3);

#pragma unroll
    for (int m = 1; m < 64; m <<= 1)
        s += __shfl_xor(s, m, 64);

    if (lane == 0) rowsum[row] = s;        // 32 KiB total — negligible
}

// ---------- Pass 2: pure-write outer product. One wave per 4 rows. ----------
// w (16 KiB) preloaded into registers once per wave; stores are nontemporal
// fire-and-forget — same regime as the 6.8 TB/s fillBuffer.
__global__ __launch_bounds__(256) void
outer_kernel(const float* __restrict__ rowsum, const float* __restrict__ w,
             float* __restrict__ out) {
    const int lane = threadIdx.x & 63;
    const int wave = (blockIdx.x * blockDim.x + threadIdx.x) >> 6;  // 0..2047
    const int row0 = wave * 4;

    const v4f* w4 = reinterpret_cast<const v4f*>(w);
    v4f wv[16];
#pragma unroll
    for (int j = 0; j < 16; ++j)
        wv[j] = w4[j * 64 + lane];         // L1/L2-hot after first touch

    float s[4];
#pragma unroll
    for (int r = 0; r < 4; ++r)
        s[r] = rowsum[row0 + r];           // L2-hot, 16 B per wave

#pragma unroll
    for (int r = 0; r < 4; ++r) {
        v4f* o4 = reinterpret_cast<v4f*>(out + (size_t)(row0 + r) * OUT_F);
        const float sr = s[r];
#pragma unroll
        for (int j = 0; j < 16; ++j) {
            v4f ov = sr * wv[j];
            __builtin_nontemporal_store(ov, &o4[j * 64 + lane]);
        }
    }
}

extern "C" void kernel_launch(void* const* d_in, const int* in_sizes, int n_in,
                              void* d_out, int out_size, void* d_ws, size_t ws_size,
                              hipStream_t stream) {
    const float* x = (const float*)d_in[0];   // [8192, 4096] fp32
    const float* w = (const float*)d_in[1];   // [1, 4096] fp32
    float* out = (float*)d_out;               // [8192, 4096] fp32
    float* rowsum = (float*)d_ws;             // 8192 floats of scratch

    // Pass 1: 8192 waves, one per row (2048 blocks x 256 threads)
    rowsum_kernel<<<BATCH / 4, 256, 0, stream>>>(x, rowsum);
    // Pass 2: 2048 waves, 4 rows each (512 blocks x 256 threads)
    outer_kernel<<<BATCH / 16, 256, 0, stream>>>(rowsum, w, out);
}